// Round 2
// baseline (119.949 us; speedup 1.0000x reference)
//
#include <hip/hip_runtime.h>
#include <hip/hip_fp16.h>

// Problem constants (match reference)
#define BB 8
#define CC 128
#define HH 112
#define WW 112
#define NTH 224            // 8 row-groups x 28 col-groups
#define RG 7               // output rows per thread

// LUT depthwise 3x3, stride 1, pad 1:
//   t1 = clip(round(w*1000)), t2 = clip(round(x_pad)), both [-255,255]
//   out = sum_taps sign(t1,t2)*lut[|t1|,|t2|] / 1000 (sign=+1 iff strictly same sign)
//
// R7 (latency-bound theory: R6's ds_read halving was neutral; no pipe is
// saturated at 14 waves/CU):
//  - Grid 1024 -> 2048: each block owns a HALF-plane (56 rows). 8 blocks/CU.
//  - Thread tile 7x8 -> 7x4 (8 rg x 28 cg): per-thread dependent chain work
//    halves (30 global loads, 120 ds_reads, acc[3][4]).
//  - __launch_bounds__(NTH, 7): cap VGPR ~72 so all 8 blocks (28 waves/CU)
//    co-reside -> 2x latency hiding.
//  - Table structure unchanged from R6 (Big = k0..k7 fp16 x8, Tail = k8 f32).
__device__ __forceinline__ unsigned pkh2(float a, float b) {
    __half2 h = __halves2half2(__float2half_rn(a), __float2half_rn(b));
    return *reinterpret_cast<unsigned*>(&h);
}

__global__ __launch_bounds__(NTH, 7)
void approx_dconv_kernel(const float* __restrict__ x,
                         const float* __restrict__ w,
                         const float* __restrict__ lut,
                         float* __restrict__ out) {
    __shared__ uint4 Big[512];    // taps k0..k7, 8 x fp16 per entry
    __shared__ float Tail[512];   // tap  k8, f32 per entry

    const int tid  = threadIdx.x;
    const int bc   = blockIdx.x >> 1;     // b*CC + c
    const int half = blockIdx.x & 1;      // 0: rows 0..55, 1: rows 56..111
    const int c    = bc % CC;

    // ---- 1) build signed 9-tap records (mirror fill) ---------------------
    const float* wc = w + c * 9;
    int  i1[9];
    bool sp[9], sn[9];
    #pragma unroll
    for (int k = 0; k < 9; ++k) {
        float t1 = rintf(wc[k] * 1000.0f);
        t1 = fminf(fmaxf(t1, -255.0f), 255.0f);
        i1[k] = (int)fabsf(t1);
        sp[k] = (t1 > 0.0f);
        sn[k] = (t1 < 0.0f);
    }
    for (int i = tid; i < 256; i += NTH) {       // i == |t2|
        float pv[9], nv[9];
        #pragma unroll
        for (int k = 0; k < 9; ++k) {
            const float v = lut[i1[k] * 256 + i];
            pv[k] = (sp[k] && i > 0) ? v : -v;   // t2 = +i
            nv[k] = (sn[k] && i > 0) ? v : -v;   // t2 = -i
        }
        uint4 bp, bn;
        bp.x = pkh2(pv[0], pv[1]); bp.y = pkh2(pv[2], pv[3]);
        bp.z = pkh2(pv[4], pv[5]); bp.w = pkh2(pv[6], pv[7]);
        bn.x = pkh2(nv[0], nv[1]); bn.y = pkh2(nv[2], nv[3]);
        bn.z = pkh2(nv[4], nv[5]); bn.w = pkh2(nv[6], nv[7]);
        Big[255 + i] = bp;  Tail[255 + i] = pv[8];
        Big[255 - i] = bn;  Tail[255 - i] = nv[8];
    }
    __syncthreads();

    // ---- 2) compute: gather-once, scatter into 3-row acc ring ------------
    const int rg = tid / 28;                     // 0..7
    const int cg = tid % 28;                     // 0..27
    const int y0 = half * 56 + rg * RG;
    const int c0 = cg * 4;
    const float* xp = x + (size_t)bc * (HH * WW);
    float* op = out + (size_t)bc * (HH * WW);

    const char* Bb = (const char*)Big;
    const char* Tb = (const char*)Tail;
    const float cm = 0.001f;

    float acc[3][4];
    #pragma unroll
    for (int s2 = 0; s2 < 3; ++s2)
        #pragma unroll
        for (int j = 0; j < 4; ++j) acc[s2][j] = 0.0f;

    #pragma unroll
    for (int R = -1; R <= RG; ++R) {             // input row y0+R
        // quantize this input row once -> Big byte offsets (idx*16)
        int oB[6];
        const int py = y0 + R;
        if (py >= 0 && py < HH) {
            const float* rp = xp + py * WW + c0;
            float p[6];
            p[0] = (cg > 0) ? rp[-1] : 0.0f;     // left halo / zero pad
            const float4 A = *(const float4*)rp;
            p[1] = A.x;  p[2] = A.y;  p[3] = A.z;  p[4] = A.w;
            p[5] = (cg < 27) ? rp[4] : 0.0f;     // right halo / zero pad
            #pragma unroll
            for (int j = 0; j < 6; ++j) {
                const float t = __builtin_amdgcn_fmed3f(rintf(p[j]), -255.0f, 255.0f);
                oB[j] = ((int)t) * 16 + 255 * 16;          // v_lshl_add
            }
        } else {
            #pragma unroll
            for (int j = 0; j < 6; ++j) oB[j] = 255 * 16;  // t2 = 0 entry
        }

        #pragma unroll
        for (int px = 0; px < 6; ++px) {         // pixel col = c0-1+px
            const uint4 G  = *(const uint4*)(Bb + oB[px]);
            const float t8 = *(const float*)(Tb + (oB[px] >> 2));
            __half2 hh[4];
            hh[0] = *(const __half2*)&G.x; hh[1] = *(const __half2*)&G.y;
            hh[2] = *(const __half2*)&G.z; hh[3] = *(const __half2*)&G.w;
            #pragma unroll
            for (int r = 0; r < 3; ++r) {
                const int o = R + 1 - r;         // local output row touched
                if (o < 0 || o > 6) continue;    // compile-time after unroll
                float* Ar = acc[(o + 3) % 3];
                #pragma unroll
                for (int s = 0; s < 3; ++s) {
                    const int j = px - s;        // local output col
                    if (j < 0 || j > 3) continue;
                    const int k = r * 3 + s;
                    const float tv = (k == 8) ? t8
                                   : ((k & 1) ? __high2float(hh[k >> 1])
                                              : __low2float (hh[k >> 1]));
                    Ar[j] = fmaf(tv, cm, Ar[j]); // v_fma_mix_f32 for fp16 taps
                }
            }
        }

        if (R >= 1) {                            // retire completed out row R-1
            const int o = R - 1;
            float* Ar = acc[(o + 3) % 3];
            float* od = op + (y0 + o) * WW + c0;
            *(float4*)od = make_float4(Ar[0], Ar[1], Ar[2], Ar[3]);
            #pragma unroll
            for (int j = 0; j < 4; ++j) Ar[j] = 0.0f;  // slot reused at R+1
        }
    }
}

extern "C" void kernel_launch(void* const* d_in, const int* in_sizes, int n_in,
                              void* d_out, int out_size, void* d_ws, size_t ws_size,
                              hipStream_t stream) {
    const float* x   = (const float*)d_in[0];
    const float* w   = (const float*)d_in[1];
    const float* lut = (const float*)d_in[2];
    float* out = (float*)d_out;
    (void)in_sizes; (void)n_in; (void)out_size; (void)d_ws; (void)ws_size;

    const int grid = BB * CC * 2;                // 2048 blocks: one half-plane each
    approx_dconv_kernel<<<grid, NTH, 0, stream>>>(x, w, lut, out);
}

// Round 3
// 112.388 us; speedup vs baseline: 1.0673x; 1.0673x over previous
//
#include <hip/hip_runtime.h>
#include <hip/hip_fp16.h>

// Problem constants (match reference)
#define BB 8
#define CC 128
#define HH 112
#define WW 112
#define NTH 224            // 8 row-groups x 28 col-groups
#define RG 7               // output rows per thread

// LUT depthwise 3x3, stride 1, pad 1:
//   t1 = clip(round(w*1000)), t2 = clip(round(x_pad)), both [-255,255]
//   out = sum_taps sign(t1,t2)*lut[|t1|,|t2|] / 1000 (sign=+1 iff strictly same sign)
//
// R8 (latency-bound per R7 counters: all pipes <40% busy, VGPR=36 = no
// prefetch distance; loads were trapped behind per-thread bounds branches):
//  - Branch-free row loads: row address CLAMPED into [0,111], halo addresses
//    clamped into the plane -> loads always issued, always in-bounds.
//    Row/halo validity applied via cndmask on the table OFFSET (oB = 4080,
//    the t2=0 entry) instead of around the load.
//  - Explicit 1-row-ahead software pipeline: praw[2][6] double buffer
//    (compile-time parity index -> stays in VGPRs). Iteration R issues
//    row R+1's loads, then quantizes/gathers row R loaded last iteration.
//  - Table structure unchanged (Big = k0..k7 fp16 x8 -> ds_read_b128,
//    Tail = k8 f32 -> ds_read_b32).
__device__ __forceinline__ unsigned pkh2(float a, float b) {
    __half2 h = __halves2half2(__float2half_rn(a), __float2half_rn(b));
    return *reinterpret_cast<unsigned*>(&h);
}

__global__ __launch_bounds__(NTH, 7)
void approx_dconv_kernel(const float* __restrict__ x,
                         const float* __restrict__ w,
                         const float* __restrict__ lut,
                         float* __restrict__ out) {
    __shared__ uint4 Big[512];    // taps k0..k7, 8 x fp16 per entry
    __shared__ float Tail[512];   // tap  k8, f32 per entry

    const int tid  = threadIdx.x;
    const int bc   = blockIdx.x >> 1;     // b*CC + c
    const int half = blockIdx.x & 1;      // 0: rows 0..55, 1: rows 56..111
    const int c    = bc % CC;

    // ---- 1) build signed 9-tap records (mirror fill) ---------------------
    const float* wc = w + c * 9;
    int  i1[9];
    bool sp[9], sn[9];
    #pragma unroll
    for (int k = 0; k < 9; ++k) {
        float t1 = rintf(wc[k] * 1000.0f);
        t1 = fminf(fmaxf(t1, -255.0f), 255.0f);
        i1[k] = (int)fabsf(t1);
        sp[k] = (t1 > 0.0f);
        sn[k] = (t1 < 0.0f);
    }
    for (int i = tid; i < 256; i += NTH) {       // i == |t2|
        float pv[9], nv[9];
        #pragma unroll
        for (int k = 0; k < 9; ++k) {
            const float v = lut[i1[k] * 256 + i];
            pv[k] = (sp[k] && i > 0) ? v : -v;   // t2 = +i
            nv[k] = (sn[k] && i > 0) ? v : -v;   // t2 = -i
        }
        uint4 bp, bn;
        bp.x = pkh2(pv[0], pv[1]); bp.y = pkh2(pv[2], pv[3]);
        bp.z = pkh2(pv[4], pv[5]); bp.w = pkh2(pv[6], pv[7]);
        bn.x = pkh2(nv[0], nv[1]); bn.y = pkh2(nv[2], nv[3]);
        bn.z = pkh2(nv[4], nv[5]); bn.w = pkh2(nv[6], nv[7]);
        Big[255 + i] = bp;  Tail[255 + i] = pv[8];
        Big[255 - i] = bn;  Tail[255 - i] = nv[8];
    }
    __syncthreads();

    // ---- 2) compute: pipelined gather-once, scatter into 3-row acc ring --
    const int rg = tid / 28;                     // 0..7
    const int cg = tid % 28;                     // 0..27
    const int y0 = half * 56 + rg * RG;
    const int c0 = cg * 4;
    const float* xp = x + (size_t)bc * (HH * WW);
    float* op = out + (size_t)bc * (HH * WW);

    const char* Bb = (const char*)Big;
    const char* Tb = (const char*)Tail;
    const float cm = 0.001f;

    const int  loff = (cg > 0)  ? -1 : 0;        // clamped halo addresses
    const int  roff = (cg < 27) ?  4 : 3;
    const bool lval = (cg > 0);
    const bool rval = (cg < 27);

    // branch-free raw row load (always in-bounds, always issued)
    float praw[2][6];
    auto rowload = [&](int R, float* p) {
        int py = y0 + R;
        py = py < 0 ? 0 : (py > HH - 1 ? HH - 1 : py);   // clamp address only
        const float* rp = xp + py * WW + c0;
        const float4 A = *(const float4*)rp;
        const float lh = rp[loff];
        const float rh = rp[roff];
        p[0] = lval ? lh : 0.0f;
        p[1] = A.x;  p[2] = A.y;  p[3] = A.z;  p[4] = A.w;
        p[5] = rval ? rh : 0.0f;
    };

    float acc[3][4];
    #pragma unroll
    for (int s2 = 0; s2 < 3; ++s2)
        #pragma unroll
        for (int j = 0; j < 4; ++j) acc[s2][j] = 0.0f;

    rowload(-1, praw[1]);                        // parity of R=-1 is 1

    #pragma unroll
    for (int R = -1; R <= RG; ++R) {             // input row y0+R
        const int pc = R & 1;                    // compile-time after unroll
        if (R < RG) rowload(R + 1, praw[pc ^ 1]);   // prefetch next row

        // quantize row R (data loaded one iteration ago) -> byte offsets
        const int  py    = y0 + R;
        const bool rowok = ((unsigned)py < (unsigned)HH);
        const float* p = praw[pc];
        int oB[6];
        #pragma unroll
        for (int j = 0; j < 6; ++j) {
            const float t = __builtin_amdgcn_fmed3f(rintf(p[j]), -255.0f, 255.0f);
            const int   q = ((int)t) * 16 + 255 * 16;    // v_lshl_add
            oB[j] = rowok ? q : 255 * 16;                // cndmask, not branch
        }

        #pragma unroll
        for (int px = 0; px < 6; ++px) {         // pixel col = c0-1+px
            const uint4 G  = *(const uint4*)(Bb + oB[px]);
            const float t8 = *(const float*)(Tb + (oB[px] >> 2));
            __half2 hh[4];
            hh[0] = *(const __half2*)&G.x; hh[1] = *(const __half2*)&G.y;
            hh[2] = *(const __half2*)&G.z; hh[3] = *(const __half2*)&G.w;
            #pragma unroll
            for (int r = 0; r < 3; ++r) {
                const int o = R + 1 - r;         // local output row touched
                if (o < 0 || o > 6) continue;    // compile-time after unroll
                float* Ar = acc[(o + 3) % 3];
                #pragma unroll
                for (int s = 0; s < 3; ++s) {
                    const int j = px - s;        // local output col
                    if (j < 0 || j > 3) continue;
                    const int k = r * 3 + s;
                    const float tv = (k == 8) ? t8
                                   : ((k & 1) ? __high2float(hh[k >> 1])
                                              : __low2float (hh[k >> 1]));
                    Ar[j] = fmaf(tv, cm, Ar[j]); // v_fma_mix_f32 for fp16 taps
                }
            }
        }

        if (R >= 1) {                            // retire completed out row R-1
            const int o = R - 1;
            float* Ar = acc[(o + 3) % 3];
            float* od = op + (y0 + o) * WW + c0;
            *(float4*)od = make_float4(Ar[0], Ar[1], Ar[2], Ar[3]);
            #pragma unroll
            for (int j = 0; j < 4; ++j) Ar[j] = 0.0f;  // slot reused at R+1
        }
    }
}

extern "C" void kernel_launch(void* const* d_in, const int* in_sizes, int n_in,
                              void* d_out, int out_size, void* d_ws, size_t ws_size,
                              hipStream_t stream) {
    const float* x   = (const float*)d_in[0];
    const float* w   = (const float*)d_in[1];
    const float* lut = (const float*)d_in[2];
    float* out = (float*)d_out;
    (void)in_sizes; (void)n_in; (void)out_size; (void)d_ws; (void)ws_size;

    const int grid = BB * CC * 2;                // 2048 blocks: one half-plane each
    approx_dconv_kernel<<<grid, NTH, 0, stream>>>(x, w, lut, out);
}